// Round 10
// baseline (147.519 us; speedup 1.0000x reference)
//
#include <hip/hip_runtime.h>
#include <hip/hip_bf16.h>

// Problem constants
#define BB 4
#define CC 128
#define NN 4096
#define KK 32
// ws layout (floats)
#define THETA_OFF 0
#define THETA_SZ  (BB*NN*CC)          // 2097152 floats (8 MB)
#define M_OFF     (THETA_OFF + THETA_SZ)
#define M_SZ      (CC*CC)
#define B2_OFF    (M_OFF + M_SZ)
#define COEF_OFF  (B2_OFF + 128)
#define COEF_SZ   (BB*NN*KK)
#define PART_OFF  (COEF_OFF + COEF_SZ)
#define PART_SZ   (2048*256)
#define PART2_OFF (PART_OFF + PART_SZ)
#define PART2_SZ  (64*256)

__device__ __forceinline__ float dot4(float4 a, float4 b) {
    return a.x*b.x + a.y*b.y + a.z*b.z + a.w*b.w;
}

// async global->LDS DMA, 16B per lane. LDS dest is wave-uniform base
// (HW writes base + lane*16); global src is per-lane.
__device__ __forceinline__ void async_copy16(const float* g, float* l) {
    __builtin_amdgcn_global_load_lds(
        (const __attribute__((address_space(1))) void*)g,
        (__attribute__((address_space(3))) void*)l, 16, 0, 0);
}

// ---------------- Kernel WT: theta GEMM (blocks 0..511) + weight combine (512..576) ----
__global__ __launch_bounds__(256) void kWT(const float* __restrict__ x,
                                           const float* __restrict__ Wt,
                                           const float* __restrict__ bt,
                                           const float* __restrict__ Ww,
                                           const float* __restrict__ Wg,
                                           const float* __restrict__ bg,
                                           const float* __restrict__ bw,
                                           float* __restrict__ theta,
                                           float* __restrict__ M,
                                           float* __restrict__ b2) {
    __shared__ float xr[32][132];
    __shared__ float wt[128][36];
    int t = threadIdx.x;
    if (blockIdx.x >= 512) {
        int bid2 = blockIdx.x - 512;
        if (bid2 < 64) {
            int e = bid2 * 2 + (t >> 7);
            int c = t & 127;
            float acc = 0.f;
#pragma unroll 8
            for (int d = 0; d < 128; ++d)
                acc += Ww[e*128 + d] * Wg[d*128 + c];
            M[e*128 + c] = acc;
        } else if (t < 128) {
            float acc = bw[t];
            for (int d = 0; d < 128; ++d)
                acc += Ww[t*128 + d] * bg[d];
            b2[t] = acc;
        }
        return;
    }
    long base = (long)blockIdx.x * (32 * 128);
#pragma unroll
    for (int r = 0; r < 4; ++r) {
        int f = (t + 256*r) * 4;
        int dn = f >> 7, c = f & 127;
        *(float4*)&xr[dn][c] = *(const float4*)(x + base + f);
    }
    float acc[4][4] = {};
    int e0 = t & 31, dn0 = (t >> 5) * 4;
    for (int cb = 0; cb < 4; ++cb) {
        __syncthreads();
#pragma unroll
        for (int r = 0; r < 4; ++r) {
            int f = (t + 256*r) * 4;
            int d = f >> 5, cc = f & 31;
            *(float4*)&wt[d][cc] = *(const float4*)(Wt + d*128 + cb*32 + cc);
        }
        __syncthreads();
#pragma unroll
        for (int q = 0; q < 8; ++q) {
            float4 a4[4], m4[4];
#pragma unroll
            for (int j = 0; j < 4; ++j) a4[j] = *(const float4*)&xr[dn0+j][cb*32 + q*4];
#pragma unroll
            for (int i = 0; i < 4; ++i) m4[i] = *(const float4*)&wt[e0 + 32*i][q*4];
#pragma unroll
            for (int i = 0; i < 4; ++i)
#pragma unroll
                for (int j = 0; j < 4; ++j)
                    acc[i][j] += dot4(a4[j], m4[i]);
        }
    }
    __syncthreads();
#pragma unroll
    for (int i = 0; i < 4; ++i) {
        float b = bt[e0 + 32*i];
#pragma unroll
        for (int j = 0; j < 4; ++j)
            xr[dn0 + j][e0 + 32*i] = acc[i][j] + b;
    }
    __syncthreads();
#pragma unroll
    for (int r = 0; r < 4; ++r) {
        int f = (t + 256*r) * 4;
        int dn = f >> 7, c = f & 127;
        *(float4*)(theta + base + f) = *(const float4*)&xr[dn][c];
    }
}

// ---------------- Kernel A: coef = softmax_k(theta[n] . theta[idx[n,k]]) ----------------
// 8 rows per block, 2048 blocks. XCD-bijective swizzle.
__global__ __launch_bounds__(256) void kA(const int* __restrict__ gi,
                                          const float* __restrict__ theta,
                                          float* __restrict__ coefG) {
    __shared__ float tc[8][132];
    __shared__ float logits[8][33];
    int t = threadIdx.x;
    int bid = (blockIdx.x & 7) * 256 + (blockIdx.x >> 3);
    long trow0 = (long)bid * 8;
    int b = bid >> 9;
    int k = t >> 3, l8 = t & 7;
    {
        int f = t * 4;
        int dn = f >> 7, c = f & 127;
        *(float4*)&tc[dn][c] = *(const float4*)(theta + trow0*128 + f);
    }
    int idxs[8];
#pragma unroll
    for (int dn = 0; dn < 8; ++dn)
        idxs[dn] = gi[(trow0 + dn) * KK + k];
    __syncthreads();
    const float* tbat = theta + (long)b * NN * CC;
#pragma unroll 2
    for (int dn = 0; dn < 8; ++dn) {
        const float* row = tbat + (long)idxs[dn] * CC;
        float p = 0.f;
#pragma unroll
        for (int j = 0; j < 4; ++j) {
            int c = j*32 + l8*4;
            float4 g = *(const float4*)(row + c);
            float4 tcv = *(const float4*)&tc[dn][c];
            p += dot4(g, tcv);
        }
        p += __shfl_xor(p, 1);
        p += __shfl_xor(p, 2);
        p += __shfl_xor(p, 4);
        if (l8 == 0) logits[dn][k] = p;
    }
    __syncthreads();
    if (t < 64) {
        int row = t >> 3;
        float l[4];
#pragma unroll
        for (int j = 0; j < 4; ++j) l[j] = logits[row][l8 + 8*j];
        float m = fmaxf(fmaxf(l[0], l[1]), fmaxf(l[2], l[3]));
        m = fmaxf(m, __shfl_xor(m, 1));
        m = fmaxf(m, __shfl_xor(m, 2));
        m = fmaxf(m, __shfl_xor(m, 4));
        float e[4]; float s = 0.f;
#pragma unroll
        for (int j = 0; j < 4; ++j) { e[j] = __expf(l[j] - m); s += e[j]; }
        s += __shfl_xor(s, 1);
        s += __shfl_xor(s, 2);
        s += __shfl_xor(s, 4);
        float inv = 1.0f / s;
#pragma unroll
        for (int j = 0; j < 4; ++j)
            coefG[(trow0 + row) * KK + l8 + 8*j] = e[j] * inv;
    }
}

// ---------------- Kernel BC8 (fused stream + GEMM + BN partials) ----------------
// Block = 8 n-rows x all 128 channels; 2048 blocks (XCD-swizzled so adjacent
// n-tiles share an XCD for y write-combining).
// Stream: 32 chunks of 4 channels; wave w stages channel 4ch+w (1 KB = ONE
// DMA instr) into a wave-private 4-slot ring; counted vmcnt (3 in flight),
// no cross-wave barriers. Each wave computes only its own channel.
// Then in-block: y[8][128] = aggL @ M^T + b2 -> LDS transpose -> float4
// stores + per-channel BN partial sums. agg never touches global.
union SH8 {
    float ring[4][4][256];   // [slot][wave][8 rows x 32 k]  16 KB
    float mc[128][36];       // M chunk staging               18.4 KB
    float yT[128][8];        // y transpose for stores         4 KB
};

__global__ __launch_bounds__(256) void kBC8(const float* __restrict__ coefG,
                                            const float* __restrict__ feat,
                                            const float* __restrict__ Mmat,
                                            const float* __restrict__ b2v,
                                            float* __restrict__ y,
                                            float* __restrict__ partial) {
    __shared__ SH8 sh;
    __shared__ float aggL[8][132];
    int t = threadIdx.x;
    int tile8 = (blockIdx.x & 7) * 256 + (blockIdx.x >> 3);
    int b = tile8 >> 9;
    int n0 = (tile8 & 511) * 8;
    int w = t >> 6, lane = t & 63;
    int row = lane >> 3, koct = lane & 7;

    // one coef float4 per lane: (row, k-oct). Materialize before DMAs so the
    // loop's vmcnt accounting sees only DMA instructions.
    float4 cf = *(const float4*)(coefG + (size_t)tile8 * 256 + lane * 4);
    asm volatile("" :: "v"(cf.x), "v"(cf.y), "v"(cf.z), "v"(cf.w));

    const size_t S = (size_t)NN * KK;
    // wave w's channel-(4ch+w) source; lane covers bytes [lane*16, +16)
    const float* fbase = feat + ((size_t)b * CC + w) * S + (size_t)n0 * KK + lane * 4;

    // prologue: chunks 0..3 into slots 0..3
#pragma unroll
    for (int ch = 0; ch < 4; ++ch)
        async_copy16(fbase + (size_t)(ch * 4) * S, &sh.ring[ch][w][0]);

#pragma unroll
    for (int ch = 0; ch < 32; ++ch) {
        if (ch < 29)       asm volatile("s_waitcnt vmcnt(3)" ::: "memory");
        else if (ch == 29) asm volatile("s_waitcnt vmcnt(2)" ::: "memory");
        else if (ch == 30) asm volatile("s_waitcnt vmcnt(1)" ::: "memory");
        else               asm volatile("s_waitcnt vmcnt(0)" ::: "memory");
        float4 f = *(const float4*)&sh.ring[ch & 3][w][lane * 4];
        float v = dot4(f, cf);
        v += __shfl_xor(v, 1);
        v += __shfl_xor(v, 2);
        v += __shfl_xor(v, 4);
        if (koct == 0) aggL[row][ch * 4 + w] = v;
        if (ch + 4 < 32) {
            // ds_reads of this slot fully retired before the DMA can overwrite
            asm volatile("s_waitcnt lgkmcnt(0)" ::: "memory");
            async_copy16(fbase + (size_t)((ch + 4) * 4) * S, &sh.ring[ch & 3][w][0]);
        }
    }
    __syncthreads();   // all waves' aggL columns visible

    // ---- in-block GEMM: y[8][128] = aggL @ M^T ----
    float acc[4] = {0.f, 0.f, 0.f, 0.f};
    int e0 = t & 31, dn0 = t >> 5;
    for (int cb = 0; cb < 4; ++cb) {
        __syncthreads();
#pragma unroll
        for (int r = 0; r < 4; ++r) {
            int f = (t + 256*r) * 4;
            int e = f >> 5, cc = f & 31;
            *(float4*)&sh.mc[e][cc] = *(const float4*)(Mmat + e*128 + cb*32 + cc);
        }
        __syncthreads();
#pragma unroll
        for (int q = 0; q < 8; ++q) {
            float4 a4 = *(const float4*)&aggL[dn0][cb*32 + q*4];
#pragma unroll
            for (int i = 0; i < 4; ++i) {
                float4 m4 = *(const float4*)&sh.mc[e0 + 32*i][q*4];
                acc[i] += dot4(a4, m4);
            }
        }
    }
    __syncthreads();   // mc dead; yT aliases it
#pragma unroll
    for (int i = 0; i < 4; ++i) {
        int e = e0 + 32*i;
        sh.yT[e][dn0] = acc[i] + b2v[e];
    }
    __syncthreads();
    // y stores: thread t covers (e = t>>1, half = t&1) -> float4
    {
        int e = t >> 1, half = t & 1;
        float4 v = *(const float4*)&sh.yT[e][half * 4];
        *(float4*)(y + ((size_t)(b*CC + e)) * NN + n0 + half*4) = v;
    }
    // BN partials: per-channel sum/sumsq over this block's 8 rows
    if (t < 128) {
        float s = 0.f, q = 0.f;
#pragma unroll
        for (int j = 0; j < 8; ++j) {
            float v = sh.yT[t][j];
            s += v; q += v * v;
        }
        partial[(size_t)blockIdx.x * 256 + t]       = s;
        partial[(size_t)blockIdx.x * 256 + 128 + t] = q;
    }
}

// ---------------- Kernel R1: 2048 partial rows -> 64 ----------------
__global__ __launch_bounds__(256) void kR1(const float* __restrict__ partial,
                                           float* __restrict__ partial2) {
    int t = threadIdx.x;
    long b0 = (long)blockIdx.x * 32;
    float acc = 0.f;
#pragma unroll 8
    for (int j = 0; j < 32; ++j)
        acc += partial[(b0 + j) * 256 + t];
    partial2[(long)blockIdx.x * 256 + t] = acc;
}

// ---------------- Kernel Zf: fused stats (64-row reduce, L2-hot) + normalize ----------------
__global__ __launch_bounds__(256) void kZf(float* __restrict__ y,
                                           const float* __restrict__ partial2,
                                           const float* __restrict__ gamma,
                                           const float* __restrict__ beta) {
    __shared__ float buf[256];
    __shared__ float scs[128];
    __shared__ float shs[128];
    int t = threadIdx.x;
    float acc = 0.f;
#pragma unroll 8
    for (int j = 0; j < 64; ++j)
        acc += partial2[j * 256 + t];
    buf[t] = acc;
    __syncthreads();
    if (t < 128) {
        float S = buf[t], Q = buf[t + 128];
        const float invN = 1.0f / (BB * NN);
        float mean = S * invN;
        float var  = Q * invN - mean * mean;
        float sc = rsqrtf(var + 1e-5f) * gamma[t];
        scs[t] = sc;
        shs[t] = beta[t] - mean * sc;
    }
    __syncthreads();
    int idx = blockIdx.x * 256 + t;   // float4 index
#pragma unroll
    for (int r = 0; r < 2; ++r) {
        int i = idx + r * 262144;
        int e = (i >> 10) & 127;
        float sc = scs[e], sh = shs[e];
        float4 v = ((float4*)y)[i];
        v.x = v.x * sc + sh;
        v.y = v.y * sc + sh;
        v.z = v.z * sc + sh;
        v.w = v.w * sc + sh;
        ((float4*)y)[i] = v;
    }
}

extern "C" void kernel_launch(void* const* d_in, const int* in_sizes, int n_in,
                              void* d_out, int out_size, void* d_ws, size_t ws_size,
                              hipStream_t stream) {
    const int*   gi    = (const int*)d_in[0];
    const float* x     = (const float*)d_in[1];
    const float* feat  = (const float*)d_in[2];
    const float* Wt    = (const float*)d_in[3];
    const float* bt    = (const float*)d_in[4];
    const float* Wg    = (const float*)d_in[5];
    const float* bg    = (const float*)d_in[6];
    const float* Ww    = (const float*)d_in[7];
    const float* bw    = (const float*)d_in[8];
    const float* gamma = (const float*)d_in[9];
    const float* beta  = (const float*)d_in[10];

    float* y  = (float*)d_out;
    float* ws = (float*)d_ws;
    float* theta    = ws + THETA_OFF;
    float* Mmat     = ws + M_OFF;
    float* b2       = ws + B2_OFF;
    float* coefG    = ws + COEF_OFF;
    float* partial  = ws + PART_OFF;
    float* partial2 = ws + PART2_OFF;

    kWT<<<577, 256, 0, stream>>>(x, Wt, bt, Ww, Wg, bg, bw, theta, Mmat, b2);
    kA<<<2048, 256, 0, stream>>>(gi, theta, coefG);
    kBC8<<<2048, 256, 0, stream>>>(coefG, feat, Mmat, b2, y, partial);
    kR1<<<64, 256, 0, stream>>>(partial, partial2);
    kZf<<<1024, 256, 0, stream>>>(y, partial2, gamma, beta);
}

// Round 11
// 101.388 us; speedup vs baseline: 1.4550x; 1.4550x over previous
//
#include <hip/hip_runtime.h>
#include <hip/hip_bf16.h>

// Problem constants
#define BB 4
#define CC 128
#define NN 4096
#define KK 32
// ws layout (floats)
#define THETA_OFF 0
#define THETA_SZ  (BB*NN*CC)          // 2097152 floats (8 MB)
#define AGG_OFF   (THETA_OFF + THETA_SZ)
#define AGG_SZ    (BB*NN*CC)
#define M_OFF     (AGG_OFF + AGG_SZ)
#define M_SZ      (CC*CC)
#define B2_OFF    (M_OFF + M_SZ)
#define COEF_OFF  (B2_OFF + 128)
#define COEF_SZ   (BB*NN*KK)
#define PART_OFF  (COEF_OFF + COEF_SZ)
#define PART_SZ   (512*256)
#define PART2_OFF (PART_OFF + PART_SZ)
#define PART2_SZ  (64*256)

__device__ __forceinline__ float dot4(float4 a, float4 b) {
    return a.x*b.x + a.y*b.y + a.z*b.z + a.w*b.w;
}

// async global->LDS DMA, 16B per lane. LDS dest is wave-uniform base
// (HW writes base + lane*16); global src is per-lane.
__device__ __forceinline__ void async_copy16(const float* g, float* l) {
    __builtin_amdgcn_global_load_lds(
        (const __attribute__((address_space(1))) void*)g,
        (__attribute__((address_space(3))) void*)l, 16, 0, 0);
}

// XOR swizzle slot for [128][32] weight tiles: row e, float4-slot q(0..7).
// All 32 lanes (rows e0..e0+31) land on distinct 16B slots -> conflict-free
// b128 reads. Bijective per row; applied identically on write and read.
__device__ __forceinline__ int wswz(int e, int q) {
    return (q ^ (e & 7) ^ ((e >> 3) & 3)) * 4;
}

// ---------------- Kernel WT: theta GEMM (blocks 0..511) + weight combine (512..576) ----
__global__ __launch_bounds__(256) void kWT(const float* __restrict__ x,
                                           const float* __restrict__ Wt,
                                           const float* __restrict__ bt,
                                           const float* __restrict__ Ww,
                                           const float* __restrict__ Wg,
                                           const float* __restrict__ bg,
                                           const float* __restrict__ bw,
                                           float* __restrict__ theta,
                                           float* __restrict__ M,
                                           float* __restrict__ b2) {
    __shared__ float xr[32][132];
    __shared__ float wt[128][32];
    int t = threadIdx.x;
    if (blockIdx.x >= 512) {
        int bid2 = blockIdx.x - 512;
        if (bid2 < 64) {
            int e = bid2 * 2 + (t >> 7);
            int c = t & 127;
            float acc = 0.f;
#pragma unroll 8
            for (int d = 0; d < 128; ++d)
                acc += Ww[e*128 + d] * Wg[d*128 + c];
            M[e*128 + c] = acc;
        } else if (t < 128) {
            float acc = bw[t];
            for (int d = 0; d < 128; ++d)
                acc += Ww[t*128 + d] * bg[d];
            b2[t] = acc;
        }
        return;
    }
    long base = (long)blockIdx.x * (32 * 128);
#pragma unroll
    for (int r = 0; r < 4; ++r) {
        int f = (t + 256*r) * 4;
        int dn = f >> 7, c = f & 127;
        *(float4*)&xr[dn][c] = *(const float4*)(x + base + f);
    }
    float acc[4][4] = {};
    int e0 = t & 31, dn0 = (t >> 5) * 4;
    for (int cb = 0; cb < 4; ++cb) {
        __syncthreads();
#pragma unroll
        for (int r = 0; r < 4; ++r) {
            int f = (t + 256*r) * 4;
            int d = f >> 5, cc = f & 31;
            *(float4*)&wt[d][wswz(d, cc >> 2)] = *(const float4*)(Wt + d*128 + cb*32 + cc);
        }
        __syncthreads();
#pragma unroll
        for (int q = 0; q < 8; ++q) {
            int sw = wswz(e0, q);
            float4 a4[4], m4[4];
#pragma unroll
            for (int j = 0; j < 4; ++j) a4[j] = *(const float4*)&xr[dn0+j][cb*32 + q*4];
#pragma unroll
            for (int i = 0; i < 4; ++i) m4[i] = *(const float4*)&wt[e0 + 32*i][sw];
#pragma unroll
            for (int i = 0; i < 4; ++i)
#pragma unroll
                for (int j = 0; j < 4; ++j)
                    acc[i][j] += dot4(a4[j], m4[i]);
        }
    }
    __syncthreads();
#pragma unroll
    for (int i = 0; i < 4; ++i) {
        float b = bt[e0 + 32*i];
#pragma unroll
        for (int j = 0; j < 4; ++j)
            xr[dn0 + j][e0 + 32*i] = acc[i][j] + b;
    }
    __syncthreads();
#pragma unroll
    for (int r = 0; r < 4; ++r) {
        int f = (t + 256*r) * 4;
        int dn = f >> 7, c = f & 127;
        *(float4*)(theta + base + f) = *(const float4*)&xr[dn][c];
    }
}

// ---------------- Kernel A: coef = softmax_k(theta[n] . theta[idx[n,k]]) ----------------
// 8 rows per block, 2048 blocks. XCD-bijective swizzle.
__global__ __launch_bounds__(256) void kA(const int* __restrict__ gi,
                                          const float* __restrict__ theta,
                                          float* __restrict__ coefG) {
    __shared__ float tc[8][132];
    __shared__ float logits[8][33];
    int t = threadIdx.x;
    int bid = (blockIdx.x & 7) * 256 + (blockIdx.x >> 3);
    long trow0 = (long)bid * 8;
    int b = bid >> 9;
    int k = t >> 3, l8 = t & 7;
    {
        int f = t * 4;
        int dn = f >> 7, c = f & 127;
        *(float4*)&tc[dn][c] = *(const float4*)(theta + trow0*128 + f);
    }
    int idxs[8];
#pragma unroll
    for (int dn = 0; dn < 8; ++dn)
        idxs[dn] = gi[(trow0 + dn) * KK + k];
    __syncthreads();
    const float* tbat = theta + (long)b * NN * CC;
#pragma unroll 2
    for (int dn = 0; dn < 8; ++dn) {
        const float* row = tbat + (long)idxs[dn] * CC;
        float p = 0.f;
#pragma unroll
        for (int j = 0; j < 4; ++j) {
            int c = j*32 + l8*4;
            float4 g = *(const float4*)(row + c);
            float4 tcv = *(const float4*)&tc[dn][c];
            p += dot4(g, tcv);
        }
        p += __shfl_xor(p, 1);
        p += __shfl_xor(p, 2);
        p += __shfl_xor(p, 4);
        if (l8 == 0) logits[dn][k] = p;
    }
    __syncthreads();
    if (t < 64) {
        int row = t >> 3;
        float l[4];
#pragma unroll
        for (int j = 0; j < 4; ++j) l[j] = logits[row][l8 + 8*j];
        float m = fmaxf(fmaxf(l[0], l[1]), fmaxf(l[2], l[3]));
        m = fmaxf(m, __shfl_xor(m, 1));
        m = fmaxf(m, __shfl_xor(m, 2));
        m = fmaxf(m, __shfl_xor(m, 4));
        float e[4]; float s = 0.f;
#pragma unroll
        for (int j = 0; j < 4; ++j) { e[j] = __expf(l[j] - m); s += e[j]; }
        s += __shfl_xor(s, 1);
        s += __shfl_xor(s, 2);
        s += __shfl_xor(s, 4);
        float inv = 1.0f / s;
#pragma unroll
        for (int j = 0; j < 4; ++j)
            coefG[(trow0 + row) * KK + l8 + 8*j] = e[j] * inv;
    }
}

// ---------------- Kernel B: agg[n][c] = sum_k coef[n][k]*feature[b][c][n][k] ----------------
// Wave-private 2-slot DMA ring: wave w stages channel ch*4+w into its OWN
// 4KB slot and consumes it itself -> NO cross-wave barriers in the loop.
// Per-wave counted vmcnt (4 outstanding while computing, never 0 till last).
// Lane l covers (row = l>>1, k-half = l&1): 4x ds_read_b128 + 4 dot4 + 1 shfl.
__global__ __launch_bounds__(256) void kB(const float* __restrict__ coefG,
                                          const float* __restrict__ feat,
                                          float* __restrict__ aggG) {
    __shared__ float stage[4][2][32][32];   // [wave][slot][n][k] 4x2x4KB
    __shared__ float aggL[32][36];
    int t = threadIdx.x;
    int cc4 = blockIdx.x & 3;
    int tile = blockIdx.x >> 2;          // b*128 + nt
    int b = tile >> 7;
    int n0 = (tile & 127) * 32;
    int w = t >> 6, lane = t & 63;
    int row = lane >> 1, kh = lane & 1;

    // 16 coef floats for (row, k-half), materialized before any DMA issues
    const float* cfp = coefG + ((size_t)tile * 32 + row) * KK + kh * 16;
    float4 cf0 = *(const float4*)(cfp);
    float4 cf1 = *(const float4*)(cfp + 4);
    float4 cf2 = *(const float4*)(cfp + 8);
    float4 cf3 = *(const float4*)(cfp + 12);
    asm volatile("" :: "v"(cf0.x), "v"(cf0.y), "v"(cf0.z), "v"(cf0.w));
    asm volatile("" :: "v"(cf1.x), "v"(cf1.y), "v"(cf1.z), "v"(cf1.w));
    asm volatile("" :: "v"(cf2.x), "v"(cf2.y), "v"(cf2.z), "v"(cf2.w));
    asm volatile("" :: "v"(cf3.x), "v"(cf3.y), "v"(cf3.z), "v"(cf3.w));

    const size_t S = (size_t)NN * KK;
    // per-lane global src: lane L covers bytes [L*16, L*16+16) of each 1KB group
    const float* fbase = feat + ((size_t)b * CC + cc4 * 32) * S + (size_t)n0 * KK + lane * 4;
    float* myStage = &stage[w][0][0][0];

    // prologue: stage chunks 0,1 into this wave's slots 0,1 (channel ch*4+w)
#pragma unroll
    for (int ch = 0; ch < 2; ++ch) {
        const float* fc = fbase + (size_t)(ch * 4 + w) * S;
        float* ld = myStage + ch * 1024;
#pragma unroll
        for (int i = 0; i < 4; ++i)
            async_copy16(fc + i * 256, ld + i * 256);
    }

#pragma unroll
    for (int ch = 0; ch < 8; ++ch) {
        // this wave's oldest 4 DMAs (chunk ch) done; keep next chunk in flight
        if (ch < 7) asm volatile("s_waitcnt vmcnt(4)" ::: "memory");
        else        asm volatile("s_waitcnt vmcnt(0)" ::: "memory");
        const float* sl = myStage + (ch & 1) * 1024 + row * 32 + kh * 16;
        float4 f0 = *(const float4*)(sl);
        float4 f1 = *(const float4*)(sl + 4);
        float4 f2 = *(const float4*)(sl + 8);
        float4 f3 = *(const float4*)(sl + 12);
        float v = dot4(f0, cf0) + dot4(f1, cf1) + dot4(f2, cf2) + dot4(f3, cf3);
        v += __shfl_xor(v, 1);
        if (kh == 0) aggL[row][ch * 4 + w] = v;
        // restage this slot with chunk ch+2 (ds_reads already retired: the
        // dot4s' lgkmcnt wait precedes this issue in program order)
        if (ch + 2 < 8) {
            const float* fc = fbase + (size_t)((ch + 2) * 4 + w) * S;
            float* ld = myStage + (ch & 1) * 1024;
#pragma unroll
            for (int i = 0; i < 4; ++i)
                async_copy16(fc + i * 256, ld + i * 256);
        }
    }
    __syncthreads();
    int orow = t >> 3, col4 = (t & 7) * 4;
    *(float4*)(aggG + ((size_t)b * NN + n0 + orow) * CC + cc4 * 32 + col4) =
        *(const float4*)&aggL[orow][col4];
}

// ---------------- Kernel C: y = agg @ M^T + b2; BN partials ----------------
// M staging uses the XOR-swizzled [128][32] layout -> conflict-free b128 reads.
__global__ __launch_bounds__(256) void kC(const float* __restrict__ aggG,
                                          const float* __restrict__ Mmat,
                                          const float* __restrict__ b2v,
                                          float* __restrict__ y,
                                          float* __restrict__ partial) {
    __shared__ float agg[32][132];
    __shared__ float mc[128][32];
    __shared__ float pw[4][128];
    __shared__ float qw[4][128];
    int t = threadIdx.x;
    int b = blockIdx.x >> 7;
    int n0 = (blockIdx.x & 127) * 32;
    long base = (long)blockIdx.x * (32 * 128);
#pragma unroll
    for (int r = 0; r < 4; ++r) {
        int f = (t + 256*r) * 4;
        int dn = f >> 7, c = f & 127;
        *(float4*)&agg[dn][c] = *(const float4*)(aggG + base + f);
    }
    float acc[4][4] = {};
    int e0 = t & 31, dn0 = (t >> 5) * 4;
    for (int cb = 0; cb < 4; ++cb) {
        __syncthreads();
#pragma unroll
        for (int r = 0; r < 4; ++r) {
            int f = (t + 256*r) * 4;
            int e = f >> 5, cc = f & 31;
            *(float4*)&mc[e][wswz(e, cc >> 2)] = *(const float4*)(Mmat + e*128 + cb*32 + cc);
        }
        __syncthreads();
#pragma unroll
        for (int q = 0; q < 8; ++q) {
            int sw = wswz(e0, q);
            float4 a4[4], m4[4];
#pragma unroll
            for (int j = 0; j < 4; ++j) a4[j] = *(const float4*)&agg[dn0+j][cb*32 + q*4];
#pragma unroll
            for (int i = 0; i < 4; ++i) m4[i] = *(const float4*)&mc[e0 + 32*i][sw];
#pragma unroll
            for (int i = 0; i < 4; ++i)
#pragma unroll
                for (int j = 0; j < 4; ++j)
                    acc[i][j] += dot4(a4[j], m4[i]);
        }
        __syncthreads();
    }
    int w = t >> 6;
#pragma unroll
    for (int i = 0; i < 4; ++i) {
        int e = e0 + 32*i;
        float bb = b2v[e];
        float4 yv;
        yv.x = acc[i][0] + bb;
        yv.y = acc[i][1] + bb;
        yv.z = acc[i][2] + bb;
        yv.w = acc[i][3] + bb;
        *(float4*)(y + ((long)(b*CC + e)) * NN + n0 + dn0) = yv;
        float s = yv.x + yv.y + yv.z + yv.w;
        float qq = yv.x*yv.x + yv.y*yv.y + yv.z*yv.z + yv.w*yv.w;
        s  += __shfl_xor(s, 32);
        qq += __shfl_xor(qq, 32);
        if (!(t & 32)) { pw[w][e] = s; qw[w][e] = qq; }
    }
    __syncthreads();
    if (t < 128) {
        partial[(long)blockIdx.x * 256 + t]       = pw[0][t] + pw[1][t] + pw[2][t] + pw[3][t];
        partial[(long)blockIdx.x * 256 + 128 + t] = qw[0][t] + qw[1][t] + qw[2][t] + qw[3][t];
    }
}

// ---------------- Kernel R1: 512 partial rows -> 64 ----------------
__global__ __launch_bounds__(256) void kR1(const float* __restrict__ partial,
                                           float* __restrict__ partial2) {
    int t = threadIdx.x;
    long b0 = (long)blockIdx.x * 8;
    float acc = 0.f;
#pragma unroll
    for (int j = 0; j < 8; ++j)
        acc += partial[(b0 + j) * 256 + t];
    partial2[(long)blockIdx.x * 256 + t] = acc;
}

// ---------------- Kernel Zf: fused stats (64-row reduce, L2-hot) + normalize ----------------
__global__ __launch_bounds__(256) void kZf(float* __restrict__ y,
                                           const float* __restrict__ partial2,
                                           const float* __restrict__ gamma,
                                           const float* __restrict__ beta) {
    __shared__ float buf[256];
    __shared__ float scs[128];
    __shared__ float shs[128];
    int t = threadIdx.x;
    float acc = 0.f;
#pragma unroll 8
    for (int j = 0; j < 64; ++j)
        acc += partial2[j * 256 + t];
    buf[t] = acc;
    __syncthreads();
    if (t < 128) {
        float S = buf[t], Q = buf[t + 128];
        const float invN = 1.0f / (BB * NN);
        float mean = S * invN;
        float var  = Q * invN - mean * mean;
        float sc = rsqrtf(var + 1e-5f) * gamma[t];
        scs[t] = sc;
        shs[t] = beta[t] - mean * sc;
    }
    __syncthreads();
    int idx = blockIdx.x * 256 + t;   // float4 index
#pragma unroll
    for (int r = 0; r < 2; ++r) {
        int i = idx + r * 262144;
        int e = (i >> 10) & 127;
        float sc = scs[e], sh = shs[e];
        float4 v = ((float4*)y)[i];
        v.x = v.x * sc + sh;
        v.y = v.y * sc + sh;
        v.z = v.z * sc + sh;
        v.w = v.w * sc + sh;
        ((float4*)y)[i] = v;
    }
}

extern "C" void kernel_launch(void* const* d_in, const int* in_sizes, int n_in,
                              void* d_out, int out_size, void* d_ws, size_t ws_size,
                              hipStream_t stream) {
    const int*   gi    = (const int*)d_in[0];
    const float* x     = (const float*)d_in[1];
    const float* feat  = (const float*)d_in[2];
    const float* Wt    = (const float*)d_in[3];
    const float* bt    = (const float*)d_in[4];
    const float* Wg    = (const float*)d_in[5];
    const float* bg    = (const float*)d_in[6];
    const float* Ww    = (const float*)d_in[7];
    const float* bw    = (const float*)d_in[8];
    const float* gamma = (const float*)d_in[9];
    const float* beta  = (const float*)d_in[10];

    float* y  = (float*)d_out;
    float* ws = (float*)d_ws;
    float* theta    = ws + THETA_OFF;
    float* aggG     = ws + AGG_OFF;
    float* Mmat     = ws + M_OFF;
    float* b2       = ws + B2_OFF;
    float* coefG    = ws + COEF_OFF;
    float* partial  = ws + PART_OFF;
    float* partial2 = ws + PART2_OFF;

    kWT<<<577, 256, 0, stream>>>(x, Wt, bt, Ww, Wg, bg, bw, theta, Mmat, b2);
    kA<<<2048, 256, 0, stream>>>(gi, theta, coefG);
    kB<<<2048, 256, 0, stream>>>(coefG, feat, aggG);
    kC<<<512, 256, 0, stream>>>(aggG, Mmat, b2, y, partial);
    kR1<<<64, 256, 0, stream>>>(partial, partial2);
    kZf<<<1024, 256, 0, stream>>>(y, partial2, gamma, beta);
}